// Round 1
// baseline (174.860 us; speedup 1.0000x reference)
//
#include <hip/hip_runtime.h>
#include <hip/hip_bf16.h>

#define T 512
#define C 256
#define D12 12
#define HID 32
#define BN_EPS 1e-5f
#define SCALE 0.0625f

typedef __attribute__((ext_vector_type(8))) short bf16x8;
typedef __attribute__((ext_vector_type(4))) float f32x4;

static __device__ __forceinline__ short f2bf(float f) {
    __hip_bfloat16 h = __float2bfloat16(f);
    return *reinterpret_cast<short*>(&h);
}

// ---------------- k1: fused TPR MLP + column-max + bias add ----------------
// one block per (b,s); 4 waves. Layer1 f32 on VALU, layer2 via bf16 MFMA.
__global__ __launch_bounds__(256) void k1_mlp_bias(
    const float* __restrict__ x, const float* __restrict__ r,
    const float* __restrict__ w1, const float* __restrict__ b1,
    const float* __restrict__ g1, const float* __restrict__ be1,
    const float* __restrict__ m1, const float* __restrict__ v1,
    const float* __restrict__ w2, const float* __restrict__ b2,
    const float* __restrict__ g2, const float* __restrict__ be2,
    const float* __restrict__ m2, const float* __restrict__ v2,
    short* __restrict__ xbb)   // [B*T][C] bf16 output (x + bias)
{
    __shared__ float s1sh[HID];
    __shared__ float C1sh[HID];
    __shared__ float w1sh[D12 * HID];
    __shared__ float rsh[64 * D12];
    __shared__ short h1sh[64 * 40];   // 64 rows, stride 40 bf16 (pad vs bank conflicts)
    __shared__ float biassh[C];

    const int tid  = threadIdx.x;
    const int lane = tid & 63;
    const int wave = tid >> 6;
    const int quad = lane >> 4;
    const int mrow = lane & 15;
    const int blk  = blockIdx.x;   // b*T + s

    if (tid < HID) {
        float s1 = g1[tid] * rsqrtf(v1[tid] + BN_EPS);
        s1sh[tid] = s1;
        C1sh[tid] = (b1[tid] - m1[tid]) * s1 + be1[tid];
    }
    __syncthreads();
    for (int i = tid; i < D12 * HID; i += 256)
        w1sh[i] = w1[i] * s1sh[i & (HID - 1)];   // fold BN scale into w1

    // B fragments: w2 with BN2 scale folded; epilogue constant per column
    bf16x8 bfrag[4];
    float  c2r[4];
    #pragma unroll
    for (int ct = 0; ct < 4; ++ct) {
        int c = wave * 64 + ct * 16 + mrow;
        float s2 = g2[c] * rsqrtf(v2[c] + BN_EPS);
        c2r[ct] = (b2[c] - m2[c]) * s2 + be2[c];
        #pragma unroll
        for (int j = 0; j < 8; ++j) {
            int k = quad * 8 + j;
            bfrag[ct][j] = f2bf(w2[k * C + c] * s2);
        }
    }

    const float* rbase = r + (size_t)blk * T * D12;
    float maxv[4] = {0.f, 0.f, 0.f, 0.f};   // relu output >= 0

    for (int t0 = 0; t0 < T; t0 += 64) {
        __syncthreads();   // protect rsh/h1sh from previous iteration readers
        #pragma unroll
        for (int i = 0; i < 3; ++i)
            rsh[i * 256 + tid] = rbase[t0 * D12 + i * 256 + tid];
        __syncthreads();
        // layer 1: h1[tt][h] = relu(r . w1' + C1)
        #pragma unroll
        for (int k = 0; k < 8; ++k) {
            int slot = k * 256 + tid;
            int tt = slot >> 5, h = slot & 31;
            float u = C1sh[h];
            #pragma unroll
            for (int d = 0; d < D12; ++d)
                u += rsh[tt * D12 + d] * w1sh[d * HID + h];
            h1sh[tt * 40 + h] = f2bf(fmaxf(u, 0.f));
        }
        __syncthreads();
        // layer 2 via MFMA + fused bn/relu/max epilogue
        #pragma unroll
        for (int rt = 0; rt < 4; ++rt) {
            bf16x8 afrag = *reinterpret_cast<const bf16x8*>(
                &h1sh[(rt * 16 + mrow) * 40 + quad * 8]);
            #pragma unroll
            for (int ct = 0; ct < 4; ++ct) {
                f32x4 acc = {0.f, 0.f, 0.f, 0.f};
                acc = __builtin_amdgcn_mfma_f32_16x16x32_bf16(afrag, bfrag[ct], acc, 0, 0, 0);
                #pragma unroll
                for (int rg = 0; rg < 4; ++rg)
                    maxv[ct] = fmaxf(maxv[ct], fmaxf(acc[rg] + c2r[ct], 0.f));
            }
        }
    }

    // reduce max across the 4 quads (same column, different rows)
    #pragma unroll
    for (int ct = 0; ct < 4; ++ct) {
        float m = maxv[ct];
        m = fmaxf(m, __shfl_xor(m, 16));
        m = fmaxf(m, __shfl_xor(m, 32));
        if (quad == 0) biassh[wave * 64 + ct * 16 + mrow] = m;
    }
    __syncthreads();
    xbb[(size_t)blk * C + tid] = f2bf(x[(size_t)blk * C + tid] + biassh[tid]);
}

// ---------------- k0: w_qkv [256][768] f32 -> wT [768][256] bf16 ----------------
__global__ __launch_bounds__(256) void k0_transpose(
    const float* __restrict__ w, short* __restrict__ wT)
{
    int idx = blockIdx.x * 256 + threadIdx.x;   // 0 .. 196607
    int e = idx >> 8, d = idx & 255;
    wT[idx] = f2bf(w[d * 768 + e]);
}

// ---------------- k2: qkv = xb @ w_qkv via MFMA ----------------
// [1024,256] x [256,768] -> [1024,768] f32. grid = 16 row-blocks x 12 col-blocks.
__global__ __launch_bounds__(256) void k2_qkv(
    const short* __restrict__ xbb,   // [1024][256] bf16
    const short* __restrict__ wT,    // [768][256] bf16 (transposed)
    float* __restrict__ qkv)         // [1024][768] f32
{
    const int tid  = threadIdx.x;
    const int lane = tid & 63;
    const int wave = tid >> 6;
    const int quad = lane >> 4;
    const int mrow = lane & 15;
    const int rb = blockIdx.x / 12;
    const int cb = blockIdx.x % 12;
    const int row0 = rb * 64 + wave * 16;
    const int col0 = cb * 64;

    f32x4 acc[4];
    #pragma unroll
    for (int ct = 0; ct < 4; ++ct) acc[ct] = (f32x4){0.f, 0.f, 0.f, 0.f};

    for (int ks = 0; ks < 8; ++ks) {
        bf16x8 afrag = *reinterpret_cast<const bf16x8*>(
            &xbb[(size_t)(row0 + mrow) * 256 + ks * 32 + quad * 8]);
        #pragma unroll
        for (int ct = 0; ct < 4; ++ct) {
            bf16x8 bfrag = *reinterpret_cast<const bf16x8*>(
                &wT[(size_t)(col0 + ct * 16 + mrow) * 256 + ks * 32 + quad * 8]);
            acc[ct] = __builtin_amdgcn_mfma_f32_16x16x32_bf16(afrag, bfrag, acc[ct], 0, 0, 0);
        }
    }
    #pragma unroll
    for (int ct = 0; ct < 4; ++ct)
        #pragma unroll
        for (int rg = 0; rg < 4; ++rg)
            qkv[(size_t)(row0 + quad * 4 + rg) * 768 + col0 + ct * 16 + mrow] = acc[ct][rg];
}

// ---------------- k3: attention (f32) ----------------
// one block per 4 query rows; phase1 dots (2 s-values/thread),
// per-wave softmax (wave i owns row i), phase2 PV (2 cols x 2 rows /thread).
__global__ __launch_bounds__(256) void k3_attn(
    const float* __restrict__ qkv, float* __restrict__ out)
{
    __shared__ float qsh[4 * C];
    __shared__ float psh[4 * T];
    __shared__ float sumsh[4];
    const int tid  = threadIdx.x;
    const int lane = tid & 63;
    const int wave = tid >> 6;
    const int b  = blockIdx.x >> 7;
    const int t0 = (blockIdx.x & 127) * 4;
    const float* qkv_b = qkv + (size_t)b * 512 * 768;

    #pragma unroll
    for (int i = 0; i < 4; ++i)
        qsh[i * 256 + tid] = qkv_b[(size_t)(t0 + i) * 768 + tid] * SCALE;
    __syncthreads();

    {   // phase 1: dots[i][s] for s = tid, tid+256
        const float* k0p = qkv_b + (size_t)tid * 768 + 256;
        const float* k1p = qkv_b + (size_t)(tid + 256) * 768 + 256;
        float a[4] = {0, 0, 0, 0}, c[4] = {0, 0, 0, 0};
        for (int d = 0; d < 256; d += 4) {
            float4 k0 = *reinterpret_cast<const float4*>(k0p + d);
            float4 k1 = *reinterpret_cast<const float4*>(k1p + d);
            #pragma unroll
            for (int i = 0; i < 4; ++i) {
                float4 q = *reinterpret_cast<const float4*>(qsh + i * 256 + d);
                a[i] += q.x * k0.x + q.y * k0.y + q.z * k0.z + q.w * k0.w;
                c[i] += q.x * k1.x + q.y * k1.y + q.z * k1.z + q.w * k1.w;
            }
        }
        #pragma unroll
        for (int i = 0; i < 4; ++i) {
            psh[i * 512 + tid] = a[i];
            psh[i * 512 + 256 + tid] = c[i];
        }
    }
    __syncthreads();

    {   // per-wave softmax: wave w owns row w (512 values, 8 per lane)
        float vals[8];
        float mx = -1e30f;
        #pragma unroll
        for (int j = 0; j < 8; ++j) {
            vals[j] = psh[wave * 512 + lane * 8 + j];
            mx = fmaxf(mx, vals[j]);
        }
        #pragma unroll
        for (int off = 32; off > 0; off >>= 1) mx = fmaxf(mx, __shfl_xor(mx, off));
        float sum = 0.f;
        #pragma unroll
        for (int j = 0; j < 8; ++j) {
            float e = __expf(vals[j] - mx);
            psh[wave * 512 + lane * 8 + j] = e;
            sum += e;
        }
        #pragma unroll
        for (int off = 32; off > 0; off >>= 1) sum += __shfl_xor(sum, off);
        if (lane == 0) sumsh[wave] = sum;
    }
    __syncthreads();

    {   // phase 2: out[rows][d] = P @ V ; thread owns 2 rows x 2 cols
        const int dp = tid & 127;
        const int rr = tid >> 7;
        float acc00 = 0, acc01 = 0, acc10 = 0, acc11 = 0;
        const float* vp = qkv_b + 512 + dp;
        for (int s = 0; s < 512; s += 4) {
            float4 p0 = *reinterpret_cast<const float4*>(psh + (rr * 2) * 512 + s);
            float4 p1 = *reinterpret_cast<const float4*>(psh + (rr * 2 + 1) * 512 + s);
            const float* pa0 = reinterpret_cast<const float*>(&p0);
            const float* pa1 = reinterpret_cast<const float*>(&p1);
            #pragma unroll
            for (int j = 0; j < 4; ++j) {
                float v0 = vp[(size_t)(s + j) * 768];
                float v1 = vp[(size_t)(s + j) * 768 + 128];
                acc00 += pa0[j] * v0; acc01 += pa0[j] * v1;
                acc10 += pa1[j] * v0; acc11 += pa1[j] * v1;
            }
        }
        float is0 = 1.f / sumsh[rr * 2];
        float is1 = 1.f / sumsh[rr * 2 + 1];
        out[(size_t)(b * 512 + t0 + rr * 2) * 256 + dp] = acc00 * is0;
        out[(size_t)(b * 512 + t0 + rr * 2) * 256 + dp + 128] = acc01 * is0;
        out[(size_t)(b * 512 + t0 + rr * 2 + 1) * 256 + dp] = acc10 * is1;
        out[(size_t)(b * 512 + t0 + rr * 2 + 1) * 256 + dp + 128] = acc11 * is1;
    }
}

extern "C" void kernel_launch(void* const* d_in, const int* in_sizes, int n_in,
                              void* d_out, int out_size, void* d_ws, size_t ws_size,
                              hipStream_t stream) {
    const float* x    = (const float*)d_in[0];
    const float* r    = (const float*)d_in[1];
    const float* w1   = (const float*)d_in[2];
    const float* b1   = (const float*)d_in[3];
    const float* g1   = (const float*)d_in[4];
    const float* be1  = (const float*)d_in[5];
    const float* m1   = (const float*)d_in[6];
    const float* v1   = (const float*)d_in[7];
    const float* w2   = (const float*)d_in[8];
    const float* b2   = (const float*)d_in[9];
    const float* g2   = (const float*)d_in[10];
    const float* be2  = (const float*)d_in[11];
    const float* m2   = (const float*)d_in[12];
    const float* v2   = (const float*)d_in[13];
    const float* wqkv = (const float*)d_in[14];
    float* out = (float*)d_out;

    // ws layout: qkv f32 [1024*768] @0 (3MB) | xbb bf16 [1024*256] @3MB | wT bf16 [768*256]
    char* ws = (char*)d_ws;
    float* qkv = (float*)ws;
    short* xbb = (short*)(ws + (size_t)1024 * 768 * 4);
    short* wT  = (short*)(ws + (size_t)1024 * 768 * 4 + (size_t)1024 * 256 * 2);

    k0_transpose<<<768, 256, 0, stream>>>(wqkv, wT);
    k1_mlp_bias<<<1024, 256, 0, stream>>>(x, r, w1, b1, g1, be1, m1, v1,
                                          w2, b2, g2, be2, m2, v2, xbb);
    k2_qkv<<<192, 256, 0, stream>>>(xbb, wT, qkv);
    k3_attn<<<256, 256, 0, stream>>>(qkv, out);
}

// Round 2
// 136.602 us; speedup vs baseline: 1.2801x; 1.2801x over previous
//
#include <hip/hip_runtime.h>
#include <hip/hip_bf16.h>

#define T 512
#define C 256
#define D12 12
#define HID 32
#define BN_EPS 1e-5f
#define SCALE 0.0625f

typedef __attribute__((ext_vector_type(8))) short bf16x8;
typedef __attribute__((ext_vector_type(4))) float f32x4;

static __device__ __forceinline__ short f2bf(float f) {
    __hip_bfloat16 h = __float2bfloat16(f);
    return *reinterpret_cast<short*>(&h);
}

// ---------------- k1: fused TPR MLP + column-max + bias add ----------------
// one block per (b,s); 4 waves. BOTH layers via bf16 MFMA (layer1 K padded 12->32).
__global__ __launch_bounds__(256) void k1_mlp_bias(
    const float* __restrict__ x, const float* __restrict__ r,
    const float* __restrict__ w1, const float* __restrict__ b1,
    const float* __restrict__ g1, const float* __restrict__ be1,
    const float* __restrict__ m1, const float* __restrict__ v1,
    const float* __restrict__ w2, const float* __restrict__ b2,
    const float* __restrict__ g2, const float* __restrict__ be2,
    const float* __restrict__ m2, const float* __restrict__ v2,
    short* __restrict__ xbb)   // [B*T][C] bf16 output (x + bias)
{
    __shared__ float s1sh[HID];
    __shared__ float C1sh[HID];
    __shared__ short w1t[32 * 32];     // [h][k] bf16, k padded to 32 (12.. = 0)
    __shared__ short rshbf[64 * 40];   // [row][k] bf16, k 12..31 zero, stride 40
    __shared__ short h1sh[64 * 40];    // [row][h] bf16, stride 40
    __shared__ float biassh[C];

    const int tid  = threadIdx.x;
    const int lane = tid & 63;
    const int wave = tid >> 6;
    const int quad = lane >> 4;
    const int mrow = lane & 15;
    const int blk  = blockIdx.x;   // b*T + s

    if (tid < HID) {
        float s1 = g1[tid] * rsqrtf(v1[tid] + BN_EPS);
        s1sh[tid] = s1;
        C1sh[tid] = (b1[tid] - m1[tid]) * s1 + be1[tid];
    }
    __syncthreads();

    // build w1t[h][k] = w1[k][h]*s1[h], k<12; else 0
    #pragma unroll
    for (int i = 0; i < 4; ++i) {
        int idx = i * 256 + tid;
        int h = idx >> 5, d = idx & 31;
        float v = (d < D12) ? w1[d * HID + h] * s1sh[h] : 0.f;
        w1t[h * 32 + d] = f2bf(v);
    }
    // zero rshbf pad region k=12..39 (written once; staging only touches k<12)
    #pragma unroll
    for (int i = 0; i < 7; ++i) {
        int idx = i * 256 + tid;          // < 1792 = 64*28
        int row = idx / 28, d = 12 + idx % 28;
        rshbf[row * 40 + d] = 0;
    }

    // layer2 B fragments: w2 with BN2 scale folded; epilogue const per column
    bf16x8 bfrag[4];
    float  c2r[4];
    #pragma unroll
    for (int ct = 0; ct < 4; ++ct) {
        int c = wave * 64 + ct * 16 + mrow;
        float s2 = g2[c] * rsqrtf(v2[c] + BN_EPS);
        c2r[ct] = (b2[c] - m2[c]) * s2 + be2[c];
        #pragma unroll
        for (int j = 0; j < 8; ++j) {
            int k = quad * 8 + j;
            bfrag[ct][j] = f2bf(w2[k * C + c] * s2);
        }
    }
    __syncthreads();

    // layer1 B fragments + consts (per wave identical)
    bf16x8 b1f[2];
    float  c1r[2];
    #pragma unroll
    for (int nt = 0; nt < 2; ++nt) {
        b1f[nt] = *reinterpret_cast<const bf16x8*>(&w1t[(nt * 16 + mrow) * 32 + quad * 8]);
        c1r[nt] = C1sh[nt * 16 + mrow];
    }

    const float* rbase = r + (size_t)blk * T * D12;
    float maxv[4] = {0.f, 0.f, 0.f, 0.f};   // relu output >= 0

    for (int t0 = 0; t0 < T; t0 += 64) {
        // stage r -> bf16 LDS (rows t0..t0+63, k<12)
        #pragma unroll
        for (int i = 0; i < 3; ++i) {
            int idx = i * 256 + tid;            // < 768 = 64*12
            int row = idx / 12, d = idx - row * 12;
            rshbf[row * 40 + d] = f2bf(rbase[t0 * D12 + idx]);
        }
        __syncthreads();
        // layer1: wave handles its 16 rows, 2 col-tiles. acc init = BN const.
        {
            bf16x8 af = *reinterpret_cast<const bf16x8*>(
                &rshbf[(wave * 16 + mrow) * 40 + quad * 8]);
            #pragma unroll
            for (int nt = 0; nt < 2; ++nt) {
                f32x4 a = {c1r[nt], c1r[nt], c1r[nt], c1r[nt]};
                a = __builtin_amdgcn_mfma_f32_16x16x32_bf16(af, b1f[nt], a, 0, 0, 0);
                #pragma unroll
                for (int rg = 0; rg < 4; ++rg)
                    h1sh[(wave * 16 + quad * 4 + rg) * 40 + nt * 16 + mrow] =
                        f2bf(fmaxf(a[rg], 0.f));
            }
        }
        __syncthreads();
        // layer2 via MFMA; acc init = BN2 const; fused relu+max epilogue
        #pragma unroll
        for (int rt = 0; rt < 4; ++rt) {
            bf16x8 a2 = *reinterpret_cast<const bf16x8*>(
                &h1sh[(rt * 16 + mrow) * 40 + quad * 8]);
            #pragma unroll
            for (int ct = 0; ct < 4; ++ct) {
                f32x4 acc = {c2r[ct], c2r[ct], c2r[ct], c2r[ct]};
                acc = __builtin_amdgcn_mfma_f32_16x16x32_bf16(a2, bfrag[ct], acc, 0, 0, 0);
                #pragma unroll
                for (int rg = 0; rg < 4; ++rg)
                    maxv[ct] = fmaxf(maxv[ct], acc[rg]);  // maxv>=0 handles relu
            }
        }
        __syncthreads();   // h1sh/rshbf safe for next iteration
    }

    // reduce max across the 4 quads (same column, different row groups)
    #pragma unroll
    for (int ct = 0; ct < 4; ++ct) {
        float m = maxv[ct];
        m = fmaxf(m, __shfl_xor(m, 16));
        m = fmaxf(m, __shfl_xor(m, 32));
        if (quad == 0) biassh[wave * 64 + ct * 16 + mrow] = m;
    }
    __syncthreads();
    xbb[(size_t)blk * C + tid] = f2bf(x[(size_t)blk * C + tid] + biassh[tid]);
}

// ---------------- k0: w_qkv [256][768] f32 -> wT [768][256] bf16 (tiled) ----
__global__ __launch_bounds__(256) void k0_transpose(
    const float* __restrict__ w, short* __restrict__ wT)
{
    __shared__ short tsh[64 * 66];
    const int tid = threadIdx.x;
    const int d0 = (blockIdx.x / 12) * 64;
    const int e0 = (blockIdx.x % 12) * 64;
    #pragma unroll
    for (int i = 0; i < 16; ++i) {
        int idx = i * 256 + tid;
        int di = idx >> 6, ej = idx & 63;
        tsh[di * 66 + ej] = f2bf(w[(size_t)(d0 + di) * 768 + e0 + ej]);
    }
    __syncthreads();
    #pragma unroll
    for (int i = 0; i < 16; ++i) {
        int idx = i * 256 + tid;
        int ei = idx >> 6, dj = idx & 63;
        wT[(size_t)(e0 + ei) * 256 + d0 + dj] = tsh[dj * 66 + ei];
    }
}

// ---------------- k2: qkv_bf = xb @ w_qkv via MFMA (bf16 out, q pre-scaled) --
__global__ __launch_bounds__(256) void k2_qkv(
    const short* __restrict__ xbb,   // [1024][256] bf16
    const short* __restrict__ wT,    // [768][256] bf16
    short* __restrict__ qbf)         // [1024][768] bf16
{
    const int tid  = threadIdx.x;
    const int lane = tid & 63;
    const int wave = tid >> 6;
    const int quad = lane >> 4;
    const int mrow = lane & 15;
    const int rb = blockIdx.x / 12;
    const int cb = blockIdx.x % 12;
    const int row0 = rb * 64 + wave * 16;
    const int col0 = cb * 64;
    const float osc = (cb < 4) ? SCALE : 1.0f;   // pre-scale q by SCALE

    f32x4 acc[4];
    #pragma unroll
    for (int ct = 0; ct < 4; ++ct) acc[ct] = (f32x4){0.f, 0.f, 0.f, 0.f};

    for (int ks = 0; ks < 8; ++ks) {
        bf16x8 afrag = *reinterpret_cast<const bf16x8*>(
            &xbb[(size_t)(row0 + mrow) * 256 + ks * 32 + quad * 8]);
        #pragma unroll
        for (int ct = 0; ct < 4; ++ct) {
            bf16x8 bfrag = *reinterpret_cast<const bf16x8*>(
                &wT[(size_t)(col0 + ct * 16 + mrow) * 256 + ks * 32 + quad * 8]);
            acc[ct] = __builtin_amdgcn_mfma_f32_16x16x32_bf16(afrag, bfrag, acc[ct], 0, 0, 0);
        }
    }
    #pragma unroll
    for (int ct = 0; ct < 4; ++ct)
        #pragma unroll
        for (int rg = 0; rg < 4; ++rg)
            qbf[(size_t)(row0 + quad * 4 + rg) * 768 + col0 + ct * 16 + mrow] =
                f2bf(acc[ct][rg] * osc);
}

// ---------------- k2b: V part of qkv_bf -> vT[b][d][s] bf16 (tiled) --------
__global__ __launch_bounds__(256) void k2b_vtrans(
    const short* __restrict__ qbf, short* __restrict__ vT)
{
    __shared__ short tsh[64 * 66];
    const int tid = threadIdx.x;
    const int r0 = (blockIdx.x >> 2) * 64;   // token tile (16 tiles)
    const int c0 = (blockIdx.x & 3) * 64;    // d tile (4 tiles)
    #pragma unroll
    for (int i = 0; i < 16; ++i) {
        int idx = i * 256 + tid;
        int ri = idx >> 6, cj = idx & 63;
        tsh[ri * 66 + cj] = qbf[(size_t)(r0 + ri) * 768 + 512 + c0 + cj];
    }
    __syncthreads();
    const int b  = r0 >> 9;
    const int rb = r0 & 511;
    #pragma unroll
    for (int i = 0; i < 16; ++i) {
        int idx = i * 256 + tid;
        int ci = idx >> 6, rj = idx & 63;
        vT[((size_t)(b * 256 + c0 + ci)) * 512 + rb + rj] = tsh[rj * 66 + ci];
    }
}

// ---------------- k3a: flash attention partials via MFMA -------------------
// block = (16-row Q-tile qt, 128-s chunk sc). 4 waves: wave w owns s 32w..32w+31
// for dots, d-tiles 4w..4w+3 for PV.
__global__ __launch_bounds__(256) void k3a_attn(
    const short* __restrict__ qbf,   // [1024][768] bf16, q pre-scaled
    const short* __restrict__ vT,    // [2][256][512] bf16
    float* __restrict__ po,          // [256][16][256] f32 partial O
    float2* __restrict__ stats)      // [256][16] (m, l)
{
    __shared__ float msh[4][16];
    __shared__ float lsh[4][16];
    __shared__ short psh[16 * 136];  // P tile [16 rows][128 s], stride 136
    const int tid  = threadIdx.x;
    const int lane = tid & 63;
    const int wave = tid >> 6;
    const int quad = lane >> 4;
    const int mrow = lane & 15;
    const int qt = blockIdx.x >> 2;
    const int sc = blockIdx.x & 3;
    const int b  = qt >> 5;
    const int row0  = qt * 16;
    const int srow0 = b * 512 + sc * 128;

    // Q A-fragments (shared by all s-tiles of this wave)
    bf16x8 qf[8];
    {
        const short* qrow = qbf + (size_t)(row0 + mrow) * 768;
        #pragma unroll
        for (int ks = 0; ks < 8; ++ks)
            qf[ks] = *reinterpret_cast<const bf16x8*>(qrow + ks * 32 + quad * 8);
    }

    // dots: 2 s-tiles per wave
    f32x4 S[2];
    #pragma unroll
    for (int st = 0; st < 2; ++st) {
        f32x4 acc = {0.f, 0.f, 0.f, 0.f};
        const short* krow = qbf + (size_t)(srow0 + wave * 32 + st * 16 + mrow) * 768 + 256;
        #pragma unroll
        for (int ks = 0; ks < 8; ++ks) {
            bf16x8 kf = *reinterpret_cast<const bf16x8*>(krow + ks * 32 + quad * 8);
            acc = __builtin_amdgcn_mfma_f32_16x16x32_bf16(qf[ks], kf, acc, 0, 0, 0);
        }
        S[st] = acc;
    }

    // row max within wave (rows m=quad*4+rg; cols spread over 16 lanes of quad)
    float mx[4];
    #pragma unroll
    for (int rg = 0; rg < 4; ++rg) mx[rg] = fmaxf(S[0][rg], S[1][rg]);
    #pragma unroll
    for (int off = 1; off < 16; off <<= 1)
        #pragma unroll
        for (int rg = 0; rg < 4; ++rg) mx[rg] = fmaxf(mx[rg], __shfl_xor(mx[rg], off));
    if (mrow == 0)
        #pragma unroll
        for (int rg = 0; rg < 4; ++rg) msh[wave][quad * 4 + rg] = mx[rg];
    __syncthreads();

    float M[4], sm[4];
    #pragma unroll
    for (int rg = 0; rg < 4; ++rg) {
        int m = quad * 4 + rg;
        M[rg] = fmaxf(fmaxf(msh[0][m], msh[1][m]), fmaxf(msh[2][m], msh[3][m]));
    }
    float ex[2][4];
    #pragma unroll
    for (int st = 0; st < 2; ++st)
        #pragma unroll
        for (int rg = 0; rg < 4; ++rg) ex[st][rg] = __expf(S[st][rg] - M[rg]);
    #pragma unroll
    for (int rg = 0; rg < 4; ++rg) sm[rg] = ex[0][rg] + ex[1][rg];
    #pragma unroll
    for (int off = 1; off < 16; off <<= 1)
        #pragma unroll
        for (int rg = 0; rg < 4; ++rg) sm[rg] += __shfl_xor(sm[rg], off);
    if (mrow == 0)
        #pragma unroll
        for (int rg = 0; rg < 4; ++rg) lsh[wave][quad * 4 + rg] = sm[rg];
    // write P tile (bf16) into A-fragment-friendly layout
    #pragma unroll
    for (int st = 0; st < 2; ++st)
        #pragma unroll
        for (int rg = 0; rg < 4; ++rg)
            psh[(quad * 4 + rg) * 136 + wave * 32 + st * 16 + mrow] = f2bf(ex[st][rg]);
    __syncthreads();

    if (wave == 0 && mrow == 0) {
        #pragma unroll
        for (int rg = 0; rg < 4; ++rg) {
            int m = quad * 4 + rg;
            float l = lsh[0][m] + lsh[1][m] + lsh[2][m] + lsh[3][m];
            stats[blockIdx.x * 16 + m] = make_float2(M[rg], l);
        }
    }

    // PV: wave owns d-tiles 4w..4w+3; k = s (4 steps of 32)
    const short* vbase = vT + (size_t)b * 256 * 512;
    f32x4 o[4];
    #pragma unroll
    for (int i = 0; i < 4; ++i) o[i] = (f32x4){0.f, 0.f, 0.f, 0.f};
    #pragma unroll
    for (int ks = 0; ks < 4; ++ks) {
        bf16x8 pf = *reinterpret_cast<const bf16x8*>(&psh[mrow * 136 + ks * 32 + quad * 8]);
        #pragma unroll
        for (int i = 0; i < 4; ++i) {
            int d0 = (wave * 4 + i) * 16;
            bf16x8 vf = *reinterpret_cast<const bf16x8*>(
                vbase + (size_t)(d0 + mrow) * 512 + sc * 128 + ks * 32 + quad * 8);
            o[i] = __builtin_amdgcn_mfma_f32_16x16x32_bf16(pf, vf, o[i], 0, 0, 0);
        }
    }
    #pragma unroll
    for (int i = 0; i < 4; ++i)
        #pragma unroll
        for (int rg = 0; rg < 4; ++rg)
            po[((size_t)blockIdx.x * 16 + quad * 4 + rg) * 256 + (wave * 4 + i) * 16 + mrow] =
                o[i][rg];
}

// ---------------- k3b: combine 4 chunk partials per row --------------------
__global__ __launch_bounds__(256) void k3b_combine(
    const float* __restrict__ po, const float2* __restrict__ stats,
    float* __restrict__ out)
{
    const int row = blockIdx.x;        // 0..1023
    const int qt = row >> 4, m = row & 15;
    const int c = threadIdx.x;
    float2 s0 = stats[(qt * 4 + 0) * 16 + m];
    float2 s1 = stats[(qt * 4 + 1) * 16 + m];
    float2 s2 = stats[(qt * 4 + 2) * 16 + m];
    float2 s3 = stats[(qt * 4 + 3) * 16 + m];
    float M = fmaxf(fmaxf(s0.x, s1.x), fmaxf(s2.x, s3.x));
    float a0 = __expf(s0.x - M), a1 = __expf(s1.x - M);
    float a2 = __expf(s2.x - M), a3 = __expf(s3.x - M);
    float inv = 1.f / (a0 * s0.y + a1 * s1.y + a2 * s2.y + a3 * s3.y);
    float acc = a0 * po[((size_t)(qt * 4 + 0) * 16 + m) * 256 + c]
              + a1 * po[((size_t)(qt * 4 + 1) * 16 + m) * 256 + c]
              + a2 * po[((size_t)(qt * 4 + 2) * 16 + m) * 256 + c]
              + a3 * po[((size_t)(qt * 4 + 3) * 16 + m) * 256 + c];
    out[(size_t)row * 256 + c] = acc * inv;
}

extern "C" void kernel_launch(void* const* d_in, const int* in_sizes, int n_in,
                              void* d_out, int out_size, void* d_ws, size_t ws_size,
                              hipStream_t stream) {
    const float* x    = (const float*)d_in[0];
    const float* r    = (const float*)d_in[1];
    const float* w1   = (const float*)d_in[2];
    const float* b1   = (const float*)d_in[3];
    const float* g1   = (const float*)d_in[4];
    const float* be1  = (const float*)d_in[5];
    const float* m1   = (const float*)d_in[6];
    const float* v1   = (const float*)d_in[7];
    const float* w2   = (const float*)d_in[8];
    const float* b2   = (const float*)d_in[9];
    const float* g2   = (const float*)d_in[10];
    const float* be2  = (const float*)d_in[11];
    const float* m2   = (const float*)d_in[12];
    const float* v2   = (const float*)d_in[13];
    const float* wqkv = (const float*)d_in[14];
    float* out = (float*)d_out;

    // ws layout (bytes):
    //   qbf   [1024*768] bf16  @ 0          (1,572,864)
    //   vT    [2*256*512] bf16 @ 1,572,864  (  524,288)
    //   xbb   [1024*256] bf16  @ 2,097,152  (  524,288)
    //   wT    [768*256] bf16   @ 2,621,440  (  393,216)
    //   po    [256*16*256] f32 @ 3,014,656  (4,194,304)
    //   stats [256*16] float2  @ 7,208,960  (   32,768)
    char* ws = (char*)d_ws;
    short*  qbf   = (short*)(ws);
    short*  vT    = (short*)(ws + 1572864);
    short*  xbb   = (short*)(ws + 2097152);
    short*  wT    = (short*)(ws + 2621440);
    float*  po    = (float*)(ws + 3014656);
    float2* stats = (float2*)(ws + 7208960);

    k0_transpose<<<48, 256, 0, stream>>>(wqkv, wT);
    k1_mlp_bias<<<1024, 256, 0, stream>>>(x, r, w1, b1, g1, be1, m1, v1,
                                          w2, b2, g2, be2, m2, v2, xbb);
    k2_qkv<<<192, 256, 0, stream>>>(xbb, wT, qbf);
    k2b_vtrans<<<64, 256, 0, stream>>>(qbf, vT);
    k3a_attn<<<256, 256, 0, stream>>>(qbf, vT, po, stats);
    k3b_combine<<<1024, 256, 0, stream>>>(po, stats, out);
}